// Round 3
// baseline (117.777 us; speedup 1.0000x reference)
//
#include <hip/hip_runtime.h>

// LightConv: B=8, T=1024, H=8, S=64, K=31, C=512 (all fp32)
// out[b,t,h*S+s] = sum_k softmax_k(filters[b,t,h,:])[k] * x[b, t+k-15, h*S+s] + bias[h*S+s]
//
// R10 == R9 resubmitted (rounds 0-2 all failed on GPUAcquisitionTimeout; holding
// the candidate stable so the first successful bench attributes both stacked
// changes via disjoint counters: OccupancyPercent->R8, TCC_HIT/FETCH_SIZE->R9).
//
// R8: occupancy-first: 1024 blocks (16 t-tiles x 8 h x 8 b), 1 tile/block,
//     single-buffer LDS 33.8KB -> 4 blocks/CU; 8-slot v4 ring buffer -> ~90 VGPR
//     -> 16 waves/CU (prior xw[35] design: ~200 VGPR, 8 waves/CU).
// R9: XCD-aware swizzle wid=(bid&7)<<7|bid>>3 (bijective, 1024%8==0): each XCD
//     gets one batch b; its x (2MB) fits the 4MB private L2 -> halo re-reads hit L2.
// Bank-conflict audit (round 2): xs compute reads are uniform 8 words/bank =
//     the 1024B/wave structural floor for ds_read_b128 -> no swizzle needed.

#define TDIM 1024
#define HH 8
#define SS 64
#define KK 31
#define CC 512
#define HK 248
#define TTILE 64
#define WIN 96
#define PAD 15
#define WSTRIDE 36
#define NBLK 1024

typedef float v4 __attribute__((ext_vector_type(4)));

__global__ __launch_bounds__(256, 4)
void lightconv_kernel(const float* __restrict__ xg,
                      const float* __restrict__ fg,
                      const float* __restrict__ bg,
                      float* __restrict__ og)
{
    __shared__ float xs[WIN * SS];          // 24576 B
    __shared__ float ws[TTILE * WSTRIDE];   //  9216 B

    const int tid = threadIdx.x;

    // XCD-chunked work remap: XCD x processes work ids [x*128, (x+1)*128)
    const int wid = ((blockIdx.x & 7) << 7) | (blockIdx.x >> 3);

    const int tx = wid & 15;
    const int h  = (wid >> 4) & 7;
    const int b  = wid >> 7;                   // 0..7
    const int t0 = tx * TTILE;

    const int frow  = tid >> 2;                // softmax: 4 threads per t-row
    const int fbase = (tid & 3) * 8;

    const int sq = (tid & 15) << 2;            // compute: 4 t x 4 ch per thread
    const int tb = (tid >> 4) << 2;

    const bool interior = (tx != 0) && (tx != 15);

    // ---- stage x tile (DMA flies across filter-load + softmax) ----
    const float* xb = xg + ((size_t)b * TDIM) * CC + h * SS;
    if (interior) {
        #pragma unroll
        for (int i = 0; i < 6; ++i) {
            int f  = tid + i * 256;            // quad 0..1535
            int r  = f >> 4;                   // row 0..95
            int c4 = (f & 15) << 2;            // ch 0..60
            const float* gp = xb + (size_t)(t0 - PAD + r) * CC + c4;
            __builtin_amdgcn_global_load_lds(
                (const __attribute__((address_space(1))) void*)gp,
                (__attribute__((address_space(3))) void*)&xs[f << 2],
                16, 0, 0);
        }
    } else {
        #pragma unroll
        for (int i = 0; i < 6; ++i) {
            int f  = tid + i * 256;
            int r  = f >> 4;
            int c4 = (f & 15) << 2;
            int t  = t0 - PAD + r;
            v4 v = (v4)(0.f);
            if ((unsigned)t < (unsigned)TDIM)
                v = *reinterpret_cast<const v4*>(xb + (size_t)t * CC + c4);
            *reinterpret_cast<v4*>(&xs[f << 2]) = v;
        }
    }

    // ---- filters + softmax -> ws ----
    {
        float v[8];
        const float* fp = fg + (size_t)(b * TDIM + t0 + frow) * HK + h * KK + fbase;
        #pragma unroll
        for (int j = 0; j < 8; ++j)
            v[j] = (fbase + j < KK) ? fp[j] : -1e30f;

        float m = v[0];
        #pragma unroll
        for (int j = 1; j < 8; ++j) m = fmaxf(m, v[j]);
        m = fmaxf(m, __shfl_xor(m, 1, 4));
        m = fmaxf(m, __shfl_xor(m, 2, 4));
        float s = 0.f;
        #pragma unroll
        for (int j = 0; j < 8; ++j) { v[j] = __expf(v[j] - m); s += v[j]; }
        s += __shfl_xor(s, 1, 4);
        s += __shfl_xor(s, 2, 4);
        float inv = 1.f / s;
        #pragma unroll
        for (int j = 0; j < 8; ++j)
            if (fbase + j < 32)
                ws[frow * WSTRIDE + fbase + j] = v[j] * inv;   // tap 31 -> weight 0
    }

    v4 bias4 = *reinterpret_cast<const v4*>(bg + h * SS + sq);

    __syncthreads();   // drains DMA (vmcnt) + ws writes (lgkmcnt)

    // ---- compute: 8-slot ring buffer, 4 taps per step ----
    // invariant before step kq: slot (4*kq + i) & 7 holds row tb + 4*kq + i, i=0..7
    v4 xw[8];
    #pragma unroll
    for (int j = 0; j < 8; ++j)
        xw[j] = *reinterpret_cast<const v4*>(&xs[(tb + j) * SS + sq]);

    v4 acc[4];
    #pragma unroll
    for (int tt = 0; tt < 4; ++tt) acc[tt] = bias4;

    #pragma unroll
    for (int kq = 0; kq < 8; ++kq) {
        v4 w4[4];
        #pragma unroll
        for (int tt = 0; tt < 4; ++tt)
            w4[tt] = *reinterpret_cast<const v4*>(
                &ws[(tb + tt) * WSTRIDE + (kq << 2)]);

        #pragma unroll
        for (int tt = 0; tt < 4; ++tt) {
            #pragma unroll
            for (int m = 0; m < 4; ++m)
                acc[tt] += xw[((kq << 2) + tt + m) & 7] * w4[tt][m];  // v_pk_fma_f32 x2
        }

        if (kq < 7) {
            #pragma unroll
            for (int i = 0; i < 4; ++i)
                xw[((kq << 2) + i) & 7] = *reinterpret_cast<const v4*>(
                    &xs[(tb + (kq << 2) + 8 + i) * SS + sq]);
        }
    }

    float* ob = og + (size_t)(b * TDIM + t0 + tb) * CC + h * SS + sq;
    #pragma unroll
    for (int tt = 0; tt < 4; ++tt)
        *reinterpret_cast<v4*>(ob + (size_t)tt * CC) = acc[tt];
}

extern "C" void kernel_launch(void* const* d_in, const int* in_sizes, int n_in,
                              void* d_out, int out_size, void* d_ws, size_t ws_size,
                              hipStream_t stream)
{
    const float* x    = (const float*)d_in[0];
    const float* f    = (const float*)d_in[1];
    const float* bias = (const float*)d_in[2];
    float* out        = (float*)d_out;
    lightconv_kernel<<<dim3(NBLK), 256, 0, stream>>>(x, f, bias, out);
}

// Round 6
// 79.912 us; speedup vs baseline: 1.4738x; 1.4738x over previous
//
#include <hip/hip_runtime.h>

// LightConv: B=8, T=1024, H=8, S=64, K=31, C=512 (all fp32)
// out[b,t,h*S+s] = sum_k softmax_k(filters[b,t,h,:])[k] * x[b, t+k-15, h*S+s] + bias[h*S+s]
//
// R13 == R11 resubmitted (rounds 4-5 failed on GPUAcquisitionTimeout; holding
// the scratch-fix candidate stable for clean attribution).
//
// R11: scratch bug fixed. Round-3 counters (VGPR=64, WRITE_SIZE=97MB = 6x output,
// VALUBusy=5%, dur 52.9us) showed the rotating-index xw[8] ring was demoted to
// per-thread scratch (rule #20): ~34MB scratch footprint thrashing L2->HBM.
// Fix: 8 NAMED v4 registers x0..x7, ring rotation hand-unrolled via macros.
//
// Kept from R8/R9: 1024 blocks (16 t-tiles x 8 h x 8 b), 1 tile/block,
// single-buffer LDS 33.8KB -> 4 blocks/CU; XCD-chunked swizzle (each XCD gets
// one batch b; 2MB x-slice fits its 4MB L2 so halo re-reads hit L2).
// Static audits: ws reads 16B-aligned broadcast (free); xs reads uniform
// 8 words/bank (structural floor); VGPR liveness ~90 < 128 cap.

#define TDIM 1024
#define HH 8
#define SS 64
#define KK 31
#define CC 512
#define HK 248
#define TTILE 64
#define WIN 96
#define PAD 15
#define WSTRIDE 36
#define NBLK 1024

typedef float v4 __attribute__((ext_vector_type(4)));

__global__ __launch_bounds__(256, 4)
void lightconv_kernel(const float* __restrict__ xg,
                      const float* __restrict__ fg,
                      const float* __restrict__ bg,
                      float* __restrict__ og)
{
    __shared__ float xs[WIN * SS];          // 24576 B
    __shared__ float ws[TTILE * WSTRIDE];   //  9216 B

    const int tid = threadIdx.x;

    // XCD-chunked work remap: XCD x processes work ids [x*128, (x+1)*128)
    const int wid = ((blockIdx.x & 7) << 7) | (blockIdx.x >> 3);

    const int tx = wid & 15;
    const int h  = (wid >> 4) & 7;
    const int b  = wid >> 7;                   // 0..7
    const int t0 = tx * TTILE;

    const int frow  = tid >> 2;                // softmax: 4 threads per t-row
    const int fbase = (tid & 3) * 8;

    const int sq = (tid & 15) << 2;            // compute: 4 t x 4 ch per thread
    const int tb = (tid >> 4) << 2;

    const bool interior = (tx != 0) && (tx != 15);

    // ---- stage x tile (DMA flies across filter-load + softmax) ----
    const float* xb = xg + ((size_t)b * TDIM) * CC + h * SS;
    if (interior) {
        #pragma unroll
        for (int i = 0; i < 6; ++i) {
            int f  = tid + i * 256;            // quad 0..1535
            int r  = f >> 4;                   // row 0..95
            int c4 = (f & 15) << 2;            // ch 0..60
            const float* gp = xb + (size_t)(t0 - PAD + r) * CC + c4;
            __builtin_amdgcn_global_load_lds(
                (const __attribute__((address_space(1))) void*)gp,
                (__attribute__((address_space(3))) void*)&xs[f << 2],
                16, 0, 0);
        }
    } else {
        #pragma unroll
        for (int i = 0; i < 6; ++i) {
            int f  = tid + i * 256;
            int r  = f >> 4;
            int c4 = (f & 15) << 2;
            int t  = t0 - PAD + r;
            v4 v = (v4)(0.f);
            if ((unsigned)t < (unsigned)TDIM)
                v = *reinterpret_cast<const v4*>(xb + (size_t)t * CC + c4);
            *reinterpret_cast<v4*>(&xs[f << 2]) = v;
        }
    }

    // ---- filters + softmax -> ws ----
    {
        float v[8];
        const float* fp = fg + (size_t)(b * TDIM + t0 + frow) * HK + h * KK + fbase;
        #pragma unroll
        for (int j = 0; j < 8; ++j)
            v[j] = (fbase + j < KK) ? fp[j] : -1e30f;

        float m = v[0];
        #pragma unroll
        for (int j = 1; j < 8; ++j) m = fmaxf(m, v[j]);
        m = fmaxf(m, __shfl_xor(m, 1, 4));
        m = fmaxf(m, __shfl_xor(m, 2, 4));
        float s = 0.f;
        #pragma unroll
        for (int j = 0; j < 8; ++j) { v[j] = __expf(v[j] - m); s += v[j]; }
        s += __shfl_xor(s, 1, 4);
        s += __shfl_xor(s, 2, 4);
        float inv = 1.f / s;
        #pragma unroll
        for (int j = 0; j < 8; ++j)
            if (fbase + j < 32)
                ws[frow * WSTRIDE + fbase + j] = v[j] * inv;   // tap 31 -> weight 0
    }

    v4 bias4 = *reinterpret_cast<const v4*>(bg + h * SS + sq);

    __syncthreads();   // drains DMA (vmcnt) + ws writes (lgkmcnt)

    // ---- compute: 8 NAMED v4 regs, ring rotation hand-unrolled ----
    // invariant before step kq: slots hold xs rows tb+4*kq .. tb+4*kq+7
    v4 x0, x1, x2, x3, x4, x5, x6, x7;
    v4 acc0 = bias4, acc1 = bias4, acc2 = bias4, acc3 = bias4;

#define LOADX(DST, ROW) DST = *reinterpret_cast<const v4*>(&xs[(tb + (ROW)) * SS + sq])

    // A0..A6 hold xs rows tb+4kq .. tb+4kq+6.
    // out row tb+tt, tap k=4kq+m uses xs row tb+tt+4kq+m = A(tt+m).
#define FMA4(KQ, A0, A1, A2, A3, A4, A5, A6)                                   \
    {                                                                          \
        v4 w;                                                                  \
        w = *reinterpret_cast<const v4*>(&ws[(tb + 0) * WSTRIDE + ((KQ) << 2)]); \
        acc0 += A0 * w[0]; acc0 += A1 * w[1]; acc0 += A2 * w[2]; acc0 += A3 * w[3]; \
        w = *reinterpret_cast<const v4*>(&ws[(tb + 1) * WSTRIDE + ((KQ) << 2)]); \
        acc1 += A1 * w[0]; acc1 += A2 * w[1]; acc1 += A3 * w[2]; acc1 += A4 * w[3]; \
        w = *reinterpret_cast<const v4*>(&ws[(tb + 2) * WSTRIDE + ((KQ) << 2)]); \
        acc2 += A2 * w[0]; acc2 += A3 * w[1]; acc2 += A4 * w[2]; acc2 += A5 * w[3]; \
        w = *reinterpret_cast<const v4*>(&ws[(tb + 3) * WSTRIDE + ((KQ) << 2)]); \
        acc3 += A3 * w[0]; acc3 += A4 * w[1]; acc3 += A5 * w[2]; acc3 += A6 * w[3]; \
    }

    LOADX(x0, 0); LOADX(x1, 1); LOADX(x2, 2); LOADX(x3, 3);
    LOADX(x4, 4); LOADX(x5, 5); LOADX(x6, 6); LOADX(x7, 7);

    FMA4(0, x0, x1, x2, x3, x4, x5, x6);
    LOADX(x0,  8); LOADX(x1,  9); LOADX(x2, 10); LOADX(x3, 11);
    FMA4(1, x4, x5, x6, x7, x0, x1, x2);
    LOADX(x4, 12); LOADX(x5, 13); LOADX(x6, 14); LOADX(x7, 15);
    FMA4(2, x0, x1, x2, x3, x4, x5, x6);
    LOADX(x0, 16); LOADX(x1, 17); LOADX(x2, 18); LOADX(x3, 19);
    FMA4(3, x4, x5, x6, x7, x0, x1, x2);
    LOADX(x4, 20); LOADX(x5, 21); LOADX(x6, 22); LOADX(x7, 23);
    FMA4(4, x0, x1, x2, x3, x4, x5, x6);
    LOADX(x0, 24); LOADX(x1, 25); LOADX(x2, 26); LOADX(x3, 27);
    FMA4(5, x4, x5, x6, x7, x0, x1, x2);
    LOADX(x4, 28); LOADX(x5, 29); LOADX(x6, 30); LOADX(x7, 31);
    FMA4(6, x0, x1, x2, x3, x4, x5, x6);
    LOADX(x0, 32); LOADX(x1, 33); LOADX(x2, 34);
    FMA4(7, x4, x5, x6, x7, x0, x1, x2);

#undef LOADX
#undef FMA4

    float* ob = og + (size_t)(b * TDIM + t0 + tb) * CC + h * SS + sq;
    *reinterpret_cast<v4*>(ob + (size_t)0 * CC) = acc0;
    *reinterpret_cast<v4*>(ob + (size_t)1 * CC) = acc1;
    *reinterpret_cast<v4*>(ob + (size_t)2 * CC) = acc2;
    *reinterpret_cast<v4*>(ob + (size_t)3 * CC) = acc3;
}

extern "C" void kernel_launch(void* const* d_in, const int* in_sizes, int n_in,
                              void* d_out, int out_size, void* d_ws, size_t ws_size,
                              hipStream_t stream)
{
    const float* x    = (const float*)d_in[0];
    const float* f    = (const float*)d_in[1];
    const float* bias = (const float*)d_in[2];
    float* out        = (float*)d_out;
    lightconv_kernel<<<dim3(NBLK), 256, 0, stream>>>(x, f, bias, out);
}